// Round 2
// baseline (1449.137 us; speedup 1.0000x reference)
//
#include <hip/hip_runtime.h>
#include <hip/hip_bf16.h>
#include <math.h>

#define N_TOK 4096
#define HID   1024
#define FF    4096
#define NEXP  8

// workspace layout (bytes)
#define WS_OFF_CNT 0
#define WS_OFF_TOK 1024
#define WS_OFF_WL  (1024 + NEXP * N_TOK * 4)                    // 132096
#define WS_OFF_H   (WS_OFF_WL + NEXP * N_TOK * 4)               // 263168
#define WS_OFF_LOG (WS_OFF_H + (size_t)N_TOK * FF * 4)          // ~67.4 MB
// total required: WS_OFF_LOG + N_TOK*HID*4 ~= 84.2 MB

__device__ __forceinline__ float selu_f(float v) {
    return 1.0507009873554805f * (v > 0.f ? v : 1.6732632423543772f * expm1f(v));
}

// ---------------------------------------------------------------------------
// C = act(A @ B + bias):  A [M,K] rm, B [K,N] rm, bias [N], C [M,N] rm.
// 128x128 tile, KT=16, 256 threads, 8x8 microtile. M,N %128==0, K %16==0.
// ---------------------------------------------------------------------------
template<int ACT>
__global__ __launch_bounds__(256) void gemm_bias_act(
    const float* __restrict__ A, const float* __restrict__ B,
    const float* __restrict__ bias, float* __restrict__ C,
    int M, int N, int K)
{
    __shared__ float As[16][128];   // k-major (transposed A tile)
    __shared__ float Bs[16][128];

    const int tid = threadIdx.x;
    const int m0 = blockIdx.y * 128;
    const int n0 = blockIdx.x * 128;
    const int tx = tid & 15, ty = tid >> 4;

    float acc[8][8];
#pragma unroll
    for (int i = 0; i < 8; ++i)
#pragma unroll
        for (int j = 0; j < 8; ++j) acc[i][j] = 0.f;

    const int ar = tid >> 1;          // 0..127  (A tile row)
    const int ak = (tid & 1) * 8;     // 0 or 8  (A tile k base)
    const int br = tid >> 4;          // 0..15   (B tile row)
    const int bc = (tid & 15) * 8;    // 0..120  (B tile col base)

    const float* Aptr = A + (size_t)(m0 + ar) * K + ak;
    const float* Bbase = B + (size_t)br * N + n0 + bc;

    for (int k0 = 0; k0 < K; k0 += 16) {
        float4 a0 = *(const float4*)(Aptr + k0);
        float4 a1 = *(const float4*)(Aptr + k0 + 4);
        float4 b0 = *(const float4*)(Bbase + (size_t)k0 * N);
        float4 b1 = *(const float4*)(Bbase + (size_t)k0 * N + 4);

        As[ak + 0][ar] = a0.x; As[ak + 1][ar] = a0.y;
        As[ak + 2][ar] = a0.z; As[ak + 3][ar] = a0.w;
        As[ak + 4][ar] = a1.x; As[ak + 5][ar] = a1.y;
        As[ak + 6][ar] = a1.z; As[ak + 7][ar] = a1.w;
        *(float4*)&Bs[br][bc]     = b0;
        *(float4*)&Bs[br][bc + 4] = b1;
        __syncthreads();

#pragma unroll
        for (int k = 0; k < 16; ++k) {
            float a[8], b[8];
            *(float4*)&a[0] = *(const float4*)&As[k][ty * 8];
            *(float4*)&a[4] = *(const float4*)&As[k][ty * 8 + 4];
            *(float4*)&b[0] = *(const float4*)&Bs[k][tx * 8];
            *(float4*)&b[4] = *(const float4*)&Bs[k][tx * 8 + 4];
#pragma unroll
            for (int i = 0; i < 8; ++i)
#pragma unroll
                for (int j = 0; j < 8; ++j)
                    acc[i][j] = fmaf(a[i], b[j], acc[i][j]);
        }
        __syncthreads();
    }

#pragma unroll
    for (int i = 0; i < 8; ++i) {
        const int m = m0 + ty * 8 + i;
        float* crow = C + (size_t)m * N + n0 + tx * 8;
#pragma unroll
        for (int j = 0; j < 8; j += 4) {
            const int n = n0 + tx * 8 + j;
            float4 v;
            v.x = acc[i][j + 0] + bias[n + 0];
            v.y = acc[i][j + 1] + bias[n + 1];
            v.z = acc[i][j + 2] + bias[n + 2];
            v.w = acc[i][j + 3] + bias[n + 3];
            if (ACT) { v.x = selu_f(v.x); v.y = selu_f(v.y); v.z = selu_f(v.z); v.w = selu_f(v.w); }
            *(float4*)(crow + j) = v;
        }
    }
}

// ---------------------------------------------------------------------------
// Top-2 over each row of logits [N_TOK, HID]; exact jax.lax.top_k tie-break
// (larger value first; equal values -> lower index). Indices >= NEXP dropped.
// One wave per token; appends (token, weight) to per-expert lists.
// ---------------------------------------------------------------------------
__global__ __launch_bounds__(256) void topk_route(
    const float* __restrict__ logits,
    int* __restrict__ cnt, int* __restrict__ toklist, float* __restrict__ wlist)
{
    const int wave = threadIdx.x >> 6;
    const int lane = threadIdx.x & 63;
    const int token = blockIdx.x * 4 + wave;
    const float* row = logits + (size_t)token * HID;

    float v1 = -INFINITY, v2 = -INFINITY;
    int i1 = 0x7fffffff, i2 = 0x7fffffff;

    for (int j = lane; j < HID; j += 64) {
        float c = row[j];
        bool b1 = (c > v1) || (c == v1 && j < i1);
        if (b1) { v2 = v1; i2 = i1; v1 = c; i1 = j; }
        else {
            bool b2 = (c > v2) || (c == v2 && j < i2);
            if (b2) { v2 = c; i2 = j; }
        }
    }
#pragma unroll
    for (int off = 32; off >= 1; off >>= 1) {
        float u1 = __shfl_xor(v1, off); int j1 = __shfl_xor(i1, off);
        float u2 = __shfl_xor(v2, off); int j2 = __shfl_xor(i2, off);
        bool b1 = (u1 > v1) || (u1 == v1 && j1 < i1);
        if (b1) { v2 = v1; i2 = i1; v1 = u1; i1 = j1; }
        else {
            bool b2 = (u1 > v2) || (u1 == v2 && j1 < i2);
            if (b2) { v2 = u1; i2 = j1; }
        }
        bool c2 = (u2 > v2) || (u2 == v2 && j2 < i2);
        if (c2) { v2 = u2; i2 = j2; }
    }
    if (lane == 0) {
        float s = v1 + v2;
        if (i1 < NEXP) {
            int p = atomicAdd(&cnt[i1], 1);
            toklist[i1 * N_TOK + p] = token;
            wlist[i1 * N_TOK + p] = v1 / s;
        }
        if (i2 < NEXP) {
            int p = atomicAdd(&cnt[i2], 1);
            toklist[i2 * N_TOK + p] = token;
            wlist[i2 * N_TOK + p] = v2 / s;
        }
    }
}

// ---------------------------------------------------------------------------
// Sparse expert FFN: for each expert e, for its routed tokens t (chunks of 8):
//   out[t] += w_t * (SELU(x_t @ wi_e + bi_e) @ wo_e + bo_e)
// grid (NEXP, FSPLIT=16): each block owns a 256-wide slice of F; expert
// weights are read once per expert per chunk. Output via atomicAdd (out
// pre-zeroed; bo added only by fs==0 block).
// ---------------------------------------------------------------------------
#define TCH 8
__global__ __launch_bounds__(256) void expert_ffn(
    const float* __restrict__ x,
    const float* __restrict__ exp_wi, const float* __restrict__ exp_bi,
    const float* __restrict__ exp_wo, const float* __restrict__ exp_bo,
    const int* __restrict__ cnt, const int* __restrict__ toklist,
    const float* __restrict__ wlist, float* __restrict__ out)
{
    const int e  = blockIdx.x;
    const int fs = blockIdx.y;           // F slice [fs*256, fs*256+256)
    const int tid = threadIdx.x;
    const int c = cnt[e];
    if (c == 0) return;

    const float* wi = exp_wi + (size_t)e * HID * FF;
    const float* wo = exp_wo + (size_t)e * FF * HID;
    const float* bi = exp_bi + (size_t)e * FF;
    const float* bo = exp_bo + (size_t)e * HID;

    __shared__ float xs[TCH][HID];       // 32 KB
    __shared__ float hs[TCH][256];       // 8 KB
    __shared__ float ws_w[TCH];
    __shared__ int   ts_t[TCH];

    for (int c0 = 0; c0 < c; c0 += TCH) {
        const int nt = min(TCH, c - c0);
        if (tid < nt) {
            ts_t[tid] = toklist[e * N_TOK + c0 + tid];
            ws_w[tid] = wlist[e * N_TOK + c0 + tid];
        }
        __syncthreads();
        {   // gather x rows (zero-fill unused rows so compute is branch-free)
            const int t = tid >> 5, seg = tid & 31;     // 32 floats per thread
            float4* dst = (float4*)&xs[t][seg * 32];
            if (t < nt) {
                const float4* src = (const float4*)(x + (size_t)ts_t[t] * HID + seg * 32);
#pragma unroll
                for (int q = 0; q < 8; ++q) dst[q] = src[q];
            } else {
                float4 z = {0.f, 0.f, 0.f, 0.f};
#pragma unroll
                for (int q = 0; q < 8; ++q) dst[q] = z;
            }
        }
        __syncthreads();

        // h[t][f] = SELU(x_t . wi[:,f] + bi[f]),  f = fs*256 + tid
        {
            const int f = fs * 256 + tid;
            float acc[TCH];
#pragma unroll
            for (int t = 0; t < TCH; ++t) acc[t] = bi[f];
            for (int k = 0; k < HID; k += 4) {
                const float w0 = wi[(size_t)(k + 0) * FF + f];
                const float w1 = wi[(size_t)(k + 1) * FF + f];
                const float w2 = wi[(size_t)(k + 2) * FF + f];
                const float w3 = wi[(size_t)(k + 3) * FF + f];
#pragma unroll
                for (int t = 0; t < TCH; ++t) {
                    float4 xv = *(const float4*)&xs[t][k];
                    acc[t] = fmaf(xv.x, w0, fmaf(xv.y, w1, fmaf(xv.z, w2, fmaf(xv.w, w3, acc[t]))));
                }
            }
#pragma unroll
            for (int t = 0; t < TCH; ++t) hs[t][tid] = selu_f(acc[t]);
        }
        __syncthreads();

        // out[t][h] += w_t * (sum_{f in slice} h[t][f]*wo[f][h] (+ bo[h] if fs==0))
        {
            float acc2[TCH][4];
#pragma unroll
            for (int t = 0; t < TCH; ++t)
#pragma unroll
                for (int q = 0; q < 4; ++q) acc2[t][q] = 0.f;

            for (int f = 0; f < 256; ++f) {
                const float* worow = wo + (size_t)(fs * 256 + f) * HID + tid;
                const float w0 = worow[0];
                const float w1 = worow[256];
                const float w2 = worow[512];
                const float w3 = worow[768];
#pragma unroll
                for (int t = 0; t < TCH; ++t) {
                    const float hv = hs[t][f];
                    acc2[t][0] = fmaf(hv, w0, acc2[t][0]);
                    acc2[t][1] = fmaf(hv, w1, acc2[t][1]);
                    acc2[t][2] = fmaf(hv, w2, acc2[t][2]);
                    acc2[t][3] = fmaf(hv, w3, acc2[t][3]);
                }
            }
#pragma unroll
            for (int t = 0; t < TCH; ++t) {
                if (t < nt) {
                    const float w = ws_w[t];
                    float* orow = out + (size_t)ts_t[t] * HID + tid;
#pragma unroll
                    for (int q = 0; q < 4; ++q) {
                        float v = acc2[t][q] * w;
                        if (fs == 0) v = fmaf(bo[tid + q * 256], w, v);
                        atomicAdd(orow + q * 256, v);
                    }
                }
            }
        }
        __syncthreads();
    }
}

extern "C" void kernel_launch(void* const* d_in, const int* in_sizes, int n_in,
                              void* d_out, int out_size, void* d_ws, size_t ws_size,
                              hipStream_t stream) {
    const float* x       = (const float*)d_in[0];
    const float* gate_wi = (const float*)d_in[1];
    const float* gate_bi = (const float*)d_in[2];
    const float* gate_wo = (const float*)d_in[3];
    const float* gate_bo = (const float*)d_in[4];
    const float* exp_wi  = (const float*)d_in[5];
    const float* exp_bi  = (const float*)d_in[6];
    const float* exp_wo  = (const float*)d_in[7];
    const float* exp_bo  = (const float*)d_in[8];
    float* out = (float*)d_out;

    char* ws = (char*)d_ws;
    int*   cnt    = (int*)  (ws + WS_OFF_CNT);
    int*   tok    = (int*)  (ws + WS_OFF_TOK);
    float* wl     = (float*)(ws + WS_OFF_WL);
    float* h      = (float*)(ws + WS_OFF_H);
    float* logits = (float*)(ws + WS_OFF_LOG);

    hipMemsetAsync(d_out, 0, (size_t)out_size * sizeof(float), stream);
    hipMemsetAsync(cnt, 0, NEXP * sizeof(int), stream);

    // gate FFN (dense, fp32 for exact-enough top-k)
    gemm_bias_act<1><<<dim3(FF / 128, N_TOK / 128), 256, 0, stream>>>(
        x, gate_wi, gate_bi, h, N_TOK, FF, HID);
    gemm_bias_act<0><<<dim3(HID / 128, N_TOK / 128), 256, 0, stream>>>(
        h, gate_wo, gate_bo, logits, N_TOK, HID, FF);

    // routing
    topk_route<<<N_TOK / 4, 256, 0, stream>>>(logits, cnt, tok, wl);

    // sparse expert FFN over routed tokens only
    expert_ffn<<<dim3(NEXP, 16), 256, 0, stream>>>(
        x, exp_wi, exp_bi, exp_wo, exp_bo, cnt, tok, wl, out);
}

// Round 3
// 885.606 us; speedup vs baseline: 1.6363x; 1.6363x over previous
//
#include <hip/hip_runtime.h>
#include <math.h>

#define N_TOK 4096
#define HID   1024
#define FF    4096
#define NEXP  8

typedef unsigned short u16;
typedef __attribute__((ext_vector_type(8))) short s16x8;
typedef __attribute__((ext_vector_type(4))) float f32x4;

// ---- workspace layout (bytes) ----
#define WS_CNT    0u
#define WS_TOK    1024u
#define WS_WL     (WS_TOK + NEXP * N_TOK * 4u)          // 132096
#define WS_XHI    263424u                               // aligned past WL
#define WS_XLO    (WS_XHI + 8388608u)
#define WS_W1THI  (WS_XLO + 8388608u)
#define WS_W1TLO  (WS_W1THI + 8388608u)
#define WS_W2THI  (WS_W1TLO + 8388608u)
#define WS_W2TLO  (WS_W2THI + 8388608u)
#define WS_HHI    (WS_W2TLO + 8388608u)
#define WS_HLO    (WS_HHI + 33554432u)
#define WS_LOGITS WS_XHI   /* aliases x_hi/x_lo (16MB), dead after GEMM1 */
// total ~117.7 MB

__device__ __forceinline__ float selu_f(float v) {
    return 1.0507009873554805f * (v > 0.f ? v : 1.6732632423543772f * expm1f(v));
}

// round-to-nearest-even f32 -> bf16 bits
__device__ __forceinline__ u16 bf16_rn(float v) {
    unsigned u = __float_as_uint(v);
    return (u16)((u + 0x7fffu + ((u >> 16) & 1u)) >> 16);
}
__device__ __forceinline__ void split_bf16(float v, u16& hi, u16& lo) {
    hi = bf16_rn(v);
    float hf = __uint_as_float(((unsigned)hi) << 16);
    lo = bf16_rn(v - hf);
}

#define GLD16(g, l) __builtin_amdgcn_global_load_lds( \
    (const __attribute__((address_space(1))) void*)(g), \
    (__attribute__((address_space(3))) void*)(l), 16, 0, 0)

static __device__ __forceinline__ f32x4 mfma16(s16x8 a, s16x8 b, f32x4 c) {
    return __builtin_amdgcn_mfma_f32_16x16x32_bf16(a, b, c, 0, 0, 0);
}

// ---------------------------------------------------------------------------
// split fp32 -> bf16 hi/lo, elementwise (float4 per thread)
// ---------------------------------------------------------------------------
__global__ __launch_bounds__(256) void split_x(
    const float* __restrict__ in, u16* __restrict__ hi, u16* __restrict__ lo, int n4)
{
    int g = blockIdx.x * 256 + threadIdx.x;
    if (g >= n4) return;
    float4 v = *(const float4*)(in + (size_t)g * 4);
    u16 h0,h1,h2,h3,l0,l1,l2,l3;
    split_bf16(v.x,h0,l0); split_bf16(v.y,h1,l1);
    split_bf16(v.z,h2,l2); split_bf16(v.w,h3,l3);
    uint2 hp, lp;
    hp.x = (unsigned)h0 | ((unsigned)h1 << 16); hp.y = (unsigned)h2 | ((unsigned)h3 << 16);
    lp.x = (unsigned)l0 | ((unsigned)l1 << 16); lp.y = (unsigned)l2 | ((unsigned)l3 << 16);
    *(uint2*)(hi + (size_t)g * 4) = hp;
    *(uint2*)(lo + (size_t)g * 4) = lp;
}

// ---------------------------------------------------------------------------
// transpose + split: in [R,C] f32  ->  out_hi/out_lo [C,R] bf16
// 64x64 tiles, 256 threads.
// ---------------------------------------------------------------------------
__global__ __launch_bounds__(256) void transpose_split(
    const float* __restrict__ in, u16* __restrict__ ohi, u16* __restrict__ olo,
    int R, int C)
{
    __shared__ float t[64][65];
    const int tx = threadIdx.x & 63, ty = threadIdx.x >> 6;
    const int r0 = blockIdx.y * 64, c0 = blockIdx.x * 64;
#pragma unroll
    for (int i = 0; i < 16; ++i) {
        int r = ty * 16 + i;
        t[r][tx] = in[(size_t)(r0 + r) * C + c0 + tx];
    }
    __syncthreads();
#pragma unroll
    for (int i = 0; i < 16; ++i) {
        int oc = ty * 16 + i;                 // column of input = row of output
        float v = t[tx][oc];
        u16 h, l; split_bf16(v, h, l);
        size_t idx = (size_t)(c0 + oc) * R + r0 + tx;
        ohi[idx] = h; olo[idx] = l;
    }
}

// ---------------------------------------------------------------------------
// C = A3 @ B3 (+bias, epilogue):  virtual K-concat of {Ahi*Bhi, Alo*Bhi, Ahi*Blo}
// A* [M,K] bf16 row-major, B* [N,K] bf16 row-major (i.e. B pre-transposed).
// 128x128 tile, BK=32, 4 waves (2x2), 16x16x32 MFMA, m97 structure.
// EPI 0: OutF[m*N+n] (+bias if z==0) via atomicAdd (split-K over blockIdx.z)
// EPI 1: selu(v+bias) -> split -> OutHi/OutLo bf16
// ---------------------------------------------------------------------------
template<int EPI>
__global__ __launch_bounds__(256) void gemm3(
    const u16* __restrict__ Ahi, const u16* __restrict__ Alo,
    const u16* __restrict__ Bhi, const u16* __restrict__ Blo,
    const float* __restrict__ bias,
    u16* __restrict__ OutHi, u16* __restrict__ OutLo, float* __restrict__ OutF,
    int M, int N, int K)
{
    __shared__ u16 As[128 * 32];   // [row][k] 64B rows, 8KB
    __shared__ u16 Bs[128 * 32];

    const int tid = threadIdx.x;
    const int wave = tid >> 6, lane = tid & 63;
    const int m0 = blockIdx.y * 128, n0 = blockIdx.x * 128;
    const int wm = wave >> 1, wn = wave & 1;

    f32x4 acc[4][4];
#pragma unroll
    for (int i = 0; i < 4; ++i)
#pragma unroll
        for (int j = 0; j < 4; ++j) acc[i][j] = (f32x4){0.f, 0.f, 0.f, 0.f};

    // staging: per wave 2 insts per matrix; inst i covers rows wave*32+i*16 .. +16
    const int srow = wave * 32 + (lane >> 2);   // row for inst0 (this lane)
    const int scol = (lane & 3) * 8;            // k elems
    const size_t aG0 = (size_t)(m0 + srow) * K + scol;
    const size_t aG1 = aG0 + (size_t)16 * K;
    const size_t bG0 = (size_t)(n0 + srow) * K + scol;
    const size_t bG1 = bG0 + (size_t)16 * K;
    u16* asl0 = &As[(wave * 32) * 32];
    u16* asl1 = &As[(wave * 32 + 16) * 32];
    u16* bsl0 = &Bs[(wave * 32) * 32];
    u16* bsl1 = &Bs[(wave * 32 + 16) * 32];

    const int ktiles = K >> 5;
    const int T = 3 * ktiles;
    const int per = T / (int)gridDim.z;
    const int t0 = blockIdx.z * per, t1 = t0 + per;

    // fragment read offsets (LDS elems)
    const int fr = lane & 15, fk = (lane >> 4) * 8;
    const int aoff = (wm * 64 + fr) * 32 + fk;
    const int boff = (wn * 64 + fr) * 32 + fk;

    for (int t = t0; t < t1; ++t) {
        const int chunk = t / ktiles;
        const int k0 = (t - chunk * ktiles) << 5;
        const u16* Ap = (chunk == 1) ? Alo : Ahi;
        const u16* Bp = (chunk == 2) ? Blo : Bhi;
        GLD16(Ap + aG0 + k0, asl0);
        GLD16(Ap + aG1 + k0, asl1);
        GLD16(Bp + bG0 + k0, bsl0);
        GLD16(Bp + bG1 + k0, bsl1);
        __syncthreads();

        s16x8 a[4], b[4];
#pragma unroll
        for (int mb = 0; mb < 4; ++mb) a[mb] = *(const s16x8*)&As[aoff + mb * 512];
#pragma unroll
        for (int nb = 0; nb < 4; ++nb) b[nb] = *(const s16x8*)&Bs[boff + nb * 512];
#pragma unroll
        for (int mb = 0; mb < 4; ++mb)
#pragma unroll
            for (int nb = 0; nb < 4; ++nb)
                acc[mb][nb] = mfma16(a[mb], b[nb], acc[mb][nb]);
        __syncthreads();
    }

    // epilogue: D[row][col], col = lane&15, row = (lane>>4)*4 + r
    const int col0 = n0 + wn * 64 + fr;
    const int rbase = m0 + wm * 64 + (lane >> 4) * 4;
    float bv[4];
#pragma unroll
    for (int nb = 0; nb < 4; ++nb) bv[nb] = bias[col0 + nb * 16];

#pragma unroll
    for (int mb = 0; mb < 4; ++mb)
#pragma unroll
        for (int nb = 0; nb < 4; ++nb) {
            const int col = col0 + nb * 16;
#pragma unroll
            for (int r = 0; r < 4; ++r) {
                const int row = rbase + mb * 16 + r;
                float v = acc[mb][nb][r];
                if (EPI == 1) {
                    v = selu_f(v + bv[nb]);
                    u16 h, l; split_bf16(v, h, l);
                    OutHi[(size_t)row * N + col] = h;
                    OutLo[(size_t)row * N + col] = l;
                } else {
                    if (blockIdx.z == 0) v += bv[nb];
                    atomicAdd(&OutF[(size_t)row * N + col], v);
                }
            }
        }
}

// ---------------------------------------------------------------------------
// Top-2 over each row of logits [N_TOK, HID]; jax.lax.top_k tie-break.
// ---------------------------------------------------------------------------
__global__ __launch_bounds__(256) void topk_route(
    const float* __restrict__ logits,
    int* __restrict__ cnt, int* __restrict__ toklist, float* __restrict__ wlist)
{
    const int wave = threadIdx.x >> 6;
    const int lane = threadIdx.x & 63;
    const int token = blockIdx.x * 4 + wave;
    const float* row = logits + (size_t)token * HID;

    float v1 = -INFINITY, v2 = -INFINITY;
    int i1 = 0x7fffffff, i2 = 0x7fffffff;

    for (int j = lane; j < HID; j += 64) {
        float c = row[j];
        bool b1 = (c > v1) || (c == v1 && j < i1);
        if (b1) { v2 = v1; i2 = i1; v1 = c; i1 = j; }
        else {
            bool b2 = (c > v2) || (c == v2 && j < i2);
            if (b2) { v2 = c; i2 = j; }
        }
    }
#pragma unroll
    for (int off = 32; off >= 1; off >>= 1) {
        float u1 = __shfl_xor(v1, off); int j1 = __shfl_xor(i1, off);
        float u2 = __shfl_xor(v2, off); int j2 = __shfl_xor(i2, off);
        bool b1 = (u1 > v1) || (u1 == v1 && j1 < i1);
        if (b1) { v2 = v1; i2 = i1; v1 = u1; i1 = j1; }
        else {
            bool b2 = (u1 > v2) || (u1 == v2 && j1 < i2);
            if (b2) { v2 = u1; i2 = j1; }
        }
        bool c2 = (u2 > v2) || (u2 == v2 && j2 < i2);
        if (c2) { v2 = u2; i2 = j2; }
    }
    if (lane == 0) {
        float s = v1 + v2;
        if (i1 < NEXP) {
            int p = atomicAdd(&cnt[i1], 1);
            toklist[i1 * N_TOK + p] = token;
            wlist[i1 * N_TOK + p] = v1 / s;
        }
        if (i2 < NEXP) {
            int p = atomicAdd(&cnt[i2], 1);
            toklist[i2 * N_TOK + p] = token;
            wlist[i2 * N_TOK + p] = v2 / s;
        }
    }
}

// ---------------------------------------------------------------------------
// Sparse expert FFN (unchanged from R2: ~80us, fine for now)
// ---------------------------------------------------------------------------
#define TCH 8
__global__ __launch_bounds__(256) void expert_ffn(
    const float* __restrict__ x,
    const float* __restrict__ exp_wi, const float* __restrict__ exp_bi,
    const float* __restrict__ exp_wo, const float* __restrict__ exp_bo,
    const int* __restrict__ cnt, const int* __restrict__ toklist,
    const float* __restrict__ wlist, float* __restrict__ out)
{
    const int e  = blockIdx.x;
    const int fs = blockIdx.y;
    const int tid = threadIdx.x;
    const int c = cnt[e];
    if (c == 0) return;

    const float* wi = exp_wi + (size_t)e * HID * FF;
    const float* wo = exp_wo + (size_t)e * FF * HID;
    const float* bi = exp_bi + (size_t)e * FF;
    const float* bo = exp_bo + (size_t)e * HID;

    __shared__ float xs[TCH][HID];
    __shared__ float hs[TCH][256];
    __shared__ float ws_w[TCH];
    __shared__ int   ts_t[TCH];

    for (int c0 = 0; c0 < c; c0 += TCH) {
        const int nt = min(TCH, c - c0);
        if (tid < nt) {
            ts_t[tid] = toklist[e * N_TOK + c0 + tid];
            ws_w[tid] = wlist[e * N_TOK + c0 + tid];
        }
        __syncthreads();
        {
            const int t = tid >> 5, seg = tid & 31;
            float4* dst = (float4*)&xs[t][seg * 32];
            if (t < nt) {
                const float4* src = (const float4*)(x + (size_t)ts_t[t] * HID + seg * 32);
#pragma unroll
                for (int q = 0; q < 8; ++q) dst[q] = src[q];
            } else {
                float4 z = {0.f, 0.f, 0.f, 0.f};
#pragma unroll
                for (int q = 0; q < 8; ++q) dst[q] = z;
            }
        }
        __syncthreads();
        {
            const int f = fs * 256 + tid;
            float acc[TCH];
#pragma unroll
            for (int t = 0; t < TCH; ++t) acc[t] = bi[f];
            for (int k = 0; k < HID; k += 4) {
                const float w0 = wi[(size_t)(k + 0) * FF + f];
                const float w1 = wi[(size_t)(k + 1) * FF + f];
                const float w2 = wi[(size_t)(k + 2) * FF + f];
                const float w3 = wi[(size_t)(k + 3) * FF + f];
#pragma unroll
                for (int t = 0; t < TCH; ++t) {
                    float4 xv = *(const float4*)&xs[t][k];
                    acc[t] = fmaf(xv.x, w0, fmaf(xv.y, w1, fmaf(xv.z, w2, fmaf(xv.w, w3, acc[t]))));
                }
            }
#pragma unroll
            for (int t = 0; t < TCH; ++t) hs[t][tid] = selu_f(acc[t]);
        }
        __syncthreads();
        {
            float acc2[TCH][4];
#pragma unroll
            for (int t = 0; t < TCH; ++t)
#pragma unroll
                for (int q = 0; q < 4; ++q) acc2[t][q] = 0.f;

            for (int f = 0; f < 256; ++f) {
                const float* worow = wo + (size_t)(fs * 256 + f) * HID + tid;
                const float w0 = worow[0];
                const float w1 = worow[256];
                const float w2 = worow[512];
                const float w3 = worow[768];
#pragma unroll
                for (int t = 0; t < TCH; ++t) {
                    const float hv = hs[t][f];
                    acc2[t][0] = fmaf(hv, w0, acc2[t][0]);
                    acc2[t][1] = fmaf(hv, w1, acc2[t][1]);
                    acc2[t][2] = fmaf(hv, w2, acc2[t][2]);
                    acc2[t][3] = fmaf(hv, w3, acc2[t][3]);
                }
            }
#pragma unroll
            for (int t = 0; t < TCH; ++t) {
                if (t < nt) {
                    const float w = ws_w[t];
                    float* orow = out + (size_t)ts_t[t] * HID + tid;
#pragma unroll
                    for (int q = 0; q < 4; ++q) {
                        float v = acc2[t][q] * w;
                        if (fs == 0) v = fmaf(bo[tid + q * 256], w, v);
                        atomicAdd(orow + q * 256, v);
                    }
                }
            }
        }
        __syncthreads();
    }
}

extern "C" void kernel_launch(void* const* d_in, const int* in_sizes, int n_in,
                              void* d_out, int out_size, void* d_ws, size_t ws_size,
                              hipStream_t stream) {
    const float* x       = (const float*)d_in[0];
    const float* gate_wi = (const float*)d_in[1];
    const float* gate_bi = (const float*)d_in[2];
    const float* gate_wo = (const float*)d_in[3];
    const float* gate_bo = (const float*)d_in[4];
    const float* exp_wi  = (const float*)d_in[5];
    const float* exp_bi  = (const float*)d_in[6];
    const float* exp_wo  = (const float*)d_in[7];
    const float* exp_bo  = (const float*)d_in[8];
    float* out = (float*)d_out;

    char* ws = (char*)d_ws;
    int*   cnt    = (int*)(ws + WS_CNT);
    int*   tok    = (int*)(ws + WS_TOK);
    float* wl     = (float*)(ws + WS_WL);
    u16*   x_hi   = (u16*)(ws + WS_XHI);
    u16*   x_lo   = (u16*)(ws + WS_XLO);
    u16*   w1t_hi = (u16*)(ws + WS_W1THI);
    u16*   w1t_lo = (u16*)(ws + WS_W1TLO);
    u16*   w2t_hi = (u16*)(ws + WS_W2THI);
    u16*   w2t_lo = (u16*)(ws + WS_W2TLO);
    u16*   h_hi   = (u16*)(ws + WS_HHI);
    u16*   h_lo   = (u16*)(ws + WS_HLO);
    float* logits = (float*)(ws + WS_LOGITS);

    hipMemsetAsync(d_out, 0, (size_t)out_size * sizeof(float), stream);
    hipMemsetAsync(cnt, 0, NEXP * sizeof(int), stream);

    // fp32 -> bf16 hi/lo conversions
    split_x<<<(N_TOK * HID / 4 + 255) / 256, 256, 0, stream>>>(x, x_hi, x_lo, N_TOK * HID / 4);
    transpose_split<<<dim3(FF / 64, HID / 64), 256, 0, stream>>>(gate_wi, w1t_hi, w1t_lo, HID, FF);
    transpose_split<<<dim3(HID / 64, FF / 64), 256, 0, stream>>>(gate_wo, w2t_hi, w2t_lo, FF, HID);

    // GEMM1: h = selu(x @ gate_wi + bi), split-stored bf16 hi/lo.  M=4096,N=4096,K=1024
    gemm3<1><<<dim3(FF / 128, N_TOK / 128, 1), 256, 0, stream>>>(
        x_hi, x_lo, w1t_hi, w1t_lo, gate_bi, h_hi, h_lo, (float*)nullptr,
        N_TOK, FF, HID);

    // logits buffer aliases x_hi/x_lo: zero it only after GEMM1 consumed x
    hipMemsetAsync(logits, 0, (size_t)N_TOK * HID * sizeof(float), stream);

    // GEMM2: logits = h @ gate_wo + bo.  M=4096,N=1024,K=4096, split-K=2
    gemm3<0><<<dim3(HID / 128, N_TOK / 128, 2), 256, 0, stream>>>(
        h_hi, h_lo, w2t_hi, w2t_lo, gate_bo, (u16*)nullptr, (u16*)nullptr, logits,
        N_TOK, HID, FF);

    // routing + sparse experts
    topk_route<<<N_TOK / 4, 256, 0, stream>>>(logits, cnt, tok, wl);
    expert_ffn<<<dim3(NEXP, 16), 256, 0, stream>>>(
        x, exp_wi, exp_bi, exp_wo, exp_bo, cnt, tok, wl, out);
}